// Round 21
// baseline (98.972 us; speedup 1.0000x reference)
//
#include <hip/hip_runtime.h>

// DecoderAttention: B=8, T=1024, N=512, L=4096, D=512, F=64, BR=8
#define B_ 8
#define T_ 1024
#define N_ 512
#define L_ 4096
#define D_ 512
#define F_ 64
#define SLICES 8
#define TPS 9     // tiles per slice (72 total: 8 node + 64 leaf)
#define KSTR 72   // attn LDS row stride (bf16) for K / V^T tiles
#define PSTR 136  // proj LDS row stride (bf16) for 128-wide k-chunks

typedef __attribute__((ext_vector_type(8))) short short8;
typedef __attribute__((ext_vector_type(4))) float f32x4;

__device__ __forceinline__ unsigned short f2bf(float x){
    unsigned u = __builtin_bit_cast(unsigned, x);
    u += 0x7FFFu + ((u >> 16) & 1u);           // RNE
    return (unsigned short)(u >> 16);
}
__device__ __forceinline__ unsigned pack_bf(float lo, float hi){
    return (unsigned)f2bf(lo) | ((unsigned)f2bf(hi) << 16);
}
__device__ __forceinline__ float bf2f(unsigned short s){
    return __builtin_bit_cast(float, ((unsigned)s) << 16);
}
__device__ __forceinline__ short8 frag_from4(unsigned d0, unsigned d1, unsigned d2, unsigned d3){
    union { unsigned u[4]; short8 s; } t;
    t.u[0] = d0; t.u[1] = d1; t.u[2] = d2; t.u[3] = d3;
    return t.s;
}

// ---------------------------------------------------------------------------
// Weight prep: transposed bf16 weights + bias vectors.
// ---------------------------------------------------------------------------
__global__ __launch_bounds__(64)
void prep_kernel(const float* __restrict__ Wq, const float* __restrict__ bq,
                 const float* __restrict__ Wk, const float* __restrict__ bk,
                 const float* __restrict__ Wv, const float* __restrict__ bv,
                 unsigned short* __restrict__ Wq_t, unsigned short* __restrict__ Wkv_t,
                 float* __restrict__ bq_s, float* __restrict__ bkv)
{
    const int n = blockIdx.x;
    const int lane = threadIdx.x;
    if (n == 192) {
        bq_s[lane]   = bq[lane] * 0.125f;
        bkv[lane]    = bk[lane];
        bkv[64+lane] = bv[lane];
        return;
    }
    const int d0 = lane * 8;
    unsigned short t[8];
    if (n < 64) {
        #pragma unroll
        for (int j = 0; j < 8; ++j) t[j] = f2bf(Wq[(size_t)(d0+j)*F_ + n] * 0.125f);
        *(uint4*)&Wq_t[(size_t)n*D_ + d0] = make_uint4(
            (unsigned)t[0]|((unsigned)t[1]<<16), (unsigned)t[2]|((unsigned)t[3]<<16),
            (unsigned)t[4]|((unsigned)t[5]<<16), (unsigned)t[6]|((unsigned)t[7]<<16));
    } else {
        const int nn  = n - 64;
        const float* W = (nn < 64) ? Wk : Wv;
        const int col = nn & 63;
        #pragma unroll
        for (int j = 0; j < 8; ++j) t[j] = f2bf(W[(size_t)(d0+j)*F_ + col]);
        *(uint4*)&Wkv_t[(size_t)nn*D_ + d0] = make_uint4(
            (unsigned)t[0]|((unsigned)t[1]<<16), (unsigned)t[2]|((unsigned)t[3]<<16),
            (unsigned)t[4]|((unsigned)t[5]<<16), (unsigned)t[6]|((unsigned)t[7]<<16));
    }
}

// ---------------------------------------------------------------------------
// Fused MFMA projection, round 21: R16's verified phase math with 512-thr
// blocks and K chunked 4x128 -> LDS 43 KB -> THREE blocks/CU (three
// independent stage/compute barrier domains; R16 proved 1->2 blocks was
// the only proj win). 8 waves: wave w = (nt = w&3, m-pair = w>>2).
// Per kk-step: 2 A-reads + 1 B-read + 2 MFMA. All operands LDS (the only
// issue-clean form per R12-R19 evidence; no register staging).
// ---------------------------------------------------------------------------
template<int MODE>
__device__ __forceinline__ void proj_body(
    int r0, unsigned short* Xs, unsigned short* Ws, unsigned short* Vt_lds,
    const float* __restrict__ X,
    const unsigned short* __restrict__ Wt,
    const float* __restrict__ bias,
    const float* __restrict__ Wagg, const float* __restrict__ bagg,
    unsigned short* __restrict__ outK, float* __restrict__ outVf,
    unsigned short* __restrict__ outVt, float* __restrict__ outAgg)
{
    constexpr int NPASS = (MODE == 0) ? 1 : 2;
    const int tid = threadIdx.x;              // 0..511
    const int l = tid & 63, c = l & 15, h = l >> 4;
    const int w  = tid >> 6;                  // wave 0..7
    const int nt = w & 3;                     // n-tile within pass
    const int m0 = (w >> 2) * 2;              // first m-subtile
    const int m1 = m0 + 1;

    f32x4 aK0 = {0,0,0,0}, aK1 = {0,0,0,0};
    f32x4 aV0 = {0,0,0,0}, aV1 = {0,0,0,0};
    float pa = 0.f;                           // agg partial (MODE 2)

    #pragma unroll
    for (int kc = 0; kc < 4; ++kc) {
        // ---- stage Xs(kc): 64 rows x 128 f32 -> bf16 (4 float4/thread) ----
        #pragma unroll
        for (int j = 0; j < 4; ++j) {
            const int s = tid + j * 512;      // slot; 32 float4 per row
            const int row = s >> 5, col = s & 31;
            const float4 v = *(const float4*)(X + (size_t)(r0+row)*D_ + kc*128 + col*4);
            *(uint2*)&Xs[row*PSTR + col*4] =
                make_uint2(pack_bf(v.x, v.y), pack_bf(v.z, v.w));
        }
        // ---- stage Ws(kc, pass 0): 64 cols x 128 bf16 (2 uint4/thread) ----
        #pragma unroll
        for (int j = 0; j < 2; ++j) {
            const int s = tid + j * 512;      // slot; 16 uint4 per row
            const int row = s >> 4, ch = s & 15;
            *(uint4*)&Ws[row*PSTR + ch*8] =
                *(const uint4*)(Wt + (size_t)row*D_ + kc*128 + ch*8);
        }
        __syncthreads();

        // ---- pass 0 compute: 4 kk-steps ----
        #pragma unroll
        for (int kk = 0; kk < 4; ++kk) {
            const short8 bfr = *(const short8*)&Ws[(16*nt + c)*PSTR + kk*32 + 8*h];
            const short8 a0  = *(const short8*)&Xs[(16*m0 + c)*PSTR + kk*32 + 8*h];
            const short8 a1  = *(const short8*)&Xs[(16*m1 + c)*PSTR + kk*32 + 8*h];
            aK0 = __builtin_amdgcn_mfma_f32_16x16x32_bf16(a0, bfr, aK0, 0,0,0);
            aK1 = __builtin_amdgcn_mfma_f32_16x16x32_bf16(a1, bfr, aK1, 0,0,0);
        }
        __syncthreads();

        if constexpr (NPASS == 2) {
            // ---- stage Ws(kc, pass 1) ----
            #pragma unroll
            for (int j = 0; j < 2; ++j) {
                const int s = tid + j * 512;
                const int row = s >> 4, ch = s & 15;
                *(uint4*)&Ws[row*PSTR + ch*8] =
                    *(const uint4*)(Wt + (size_t)(64 + row)*D_ + kc*128 + ch*8);
            }
            __syncthreads();
            // ---- pass 1 compute ----
            #pragma unroll
            for (int kk = 0; kk < 4; ++kk) {
                const short8 bfr = *(const short8*)&Ws[(16*nt + c)*PSTR + kk*32 + 8*h];
                const short8 a0  = *(const short8*)&Xs[(16*m0 + c)*PSTR + kk*32 + 8*h];
                const short8 a1  = *(const short8*)&Xs[(16*m1 + c)*PSTR + kk*32 + 8*h];
                aV0 = __builtin_amdgcn_mfma_f32_16x16x32_bf16(a0, bfr, aV0, 0,0,0);
                aV1 = __builtin_amdgcn_mfma_f32_16x16x32_bf16(a1, bfr, aV1, 0,0,0);
            }
            // ---- agg partial for this k-chunk (Xs still valid here) ----
            if constexpr (MODE == 2) {
                const int row = tid >> 3, qd = tid & 7;
                const unsigned short* xr = &Xs[row*PSTR + qd*16];
                const float* wr = Wagg + kc*128 + qd*16;
                #pragma unroll
                for (int j = 0; j < 2; ++j) {
                    const short8 xv = *(const short8*)(xr + j*8);
                    const float4 wa0 = *(const float4*)(wr + j*8);
                    const float4 wa1 = *(const float4*)(wr + j*8 + 4);
                    pa += bf2f((unsigned short)xv[0])*wa0.x + bf2f((unsigned short)xv[1])*wa0.y
                        + bf2f((unsigned short)xv[2])*wa0.z + bf2f((unsigned short)xv[3])*wa0.w
                        + bf2f((unsigned short)xv[4])*wa1.x + bf2f((unsigned short)xv[5])*wa1.y
                        + bf2f((unsigned short)xv[6])*wa1.z + bf2f((unsigned short)xv[7])*wa1.w;
                }
            }
            __syncthreads();
        }
    }

    // ---- epilogue (R12/R15/R16-verified): row=r0+16m+4h+r, col=16nt+c ----
    {
        const float bc0 = bias[16*nt + c];
        #pragma unroll
        for (int r = 0; r < 4; ++r) {
            const int rowA = r0 + 16*m0 + 4*h + r;
            const int rowB = r0 + 16*m1 + 4*h + r;
            outK[(size_t)rowA*F_ + 16*nt + c] = f2bf(aK0[r] + bc0);
            outK[(size_t)rowB*F_ + 16*nt + c] = f2bf(aK1[r] + bc0);
        }
    }
    if constexpr (NPASS == 2) {
        const float bc1 = bias[64 + 16*nt + c];
        #pragma unroll
        for (int r = 0; r < 4; ++r) {
            const int rowA = r0 + 16*m0 + 4*h + r;
            const int rowB = r0 + 16*m1 + 4*h + r;
            const float v0 = aV0[r] + bc1;
            const float v1 = aV1[r] + bc1;
            if constexpr (MODE == 1) {
                outVf[(size_t)rowA*F_ + 16*nt + c] = v0;
                outVf[(size_t)rowB*F_ + 16*nt + c] = v1;
            } else {
                Vt_lds[(16*nt + c)*72 + 16*m0 + 4*h + r] = f2bf(v0);
                Vt_lds[(16*nt + c)*72 + 16*m1 + 4*h + r] = f2bf(v1);
            }
        }
    }

    if constexpr (MODE == 2) {
        // agg: reduce over the 8 qd lanes, write one logit per leaf row
        {
            const int row = tid >> 3, qd = tid & 7;
            pa += __shfl_xor(pa, 1);
            pa += __shfl_xor(pa, 2);
            pa += __shfl_xor(pa, 4);
            if (qd == 0) outAgg[r0 + row] = pa + bagg[0];
        }
        __syncthreads();              // Vt_lds complete
        // coalesced V^T writeout: f = tid>>3, 8-leaf segment
        {
            const int f = tid >> 3, seg = tid & 7;
            const int b = r0 >> 12, l0 = r0 & (L_ - 1);
            const uint4 a0 = *(const uint4*)&Vt_lds[f*72 + seg*8];
            *(uint4*)(outVt + ((size_t)(b*F_ + f))*L_ + l0 + seg*8) = a0;
        }
    }
}

// Fused projections: blocks 0..511 leaf, 512..639 target(q), 640..703 node.
__global__ __launch_bounds__(512, 6)
void proj_all(const float* __restrict__ target, const float* __restrict__ node,
              const float* __restrict__ leaf,
              const unsigned short* __restrict__ Wq_t,
              const unsigned short* __restrict__ Wkv_t,
              const float* __restrict__ bq_s, const float* __restrict__ bkv,
              const float* __restrict__ Wagg, const float* __restrict__ bagg,
              unsigned short* __restrict__ q_bf, unsigned short* __restrict__ nk_bf,
              float* __restrict__ node_v, unsigned short* __restrict__ lk_bf,
              unsigned short* __restrict__ lvt, float* __restrict__ agg)
{
    __shared__ unsigned short Xs[64 * PSTR];      // 17.4 KB
    __shared__ unsigned short Ws[64 * PSTR];      // 17.4 KB
    __shared__ unsigned short Vt_lds[64 * 72];    // 9.2 KB -> 43 KB total
    const int blk = blockIdx.x;
    if (blk < 512) {
        proj_body<2>(blk*64, Xs, Ws, Vt_lds, leaf, Wkv_t, bkv, Wagg, bagg,
                     lk_bf, nullptr, lvt, agg);
    } else if (blk < 640) {
        proj_body<0>((blk-512)*64, Xs, Ws, Vt_lds, target, Wq_t, bq_s, nullptr, nullptr,
                     q_bf, nullptr, nullptr, nullptr);
    } else {
        proj_body<1>((blk-640)*64, Xs, Ws, Vt_lds, node, Wkv_t, bkv, nullptr, nullptr,
                     nk_bf, node_v, nullptr, nullptr);
    }
}

// ---------------------------------------------------------------------------
// Fused suffix-scan + node_hat (verified round 9). One wave per (b,f).
// ---------------------------------------------------------------------------
__global__ __launch_bounds__(256)
void scan_nh_kernel(const unsigned short* __restrict__ lvt,
                    const float* __restrict__ node_v,
                    const float* __restrict__ root,
                    const float* __restrict__ agg,
                    unsigned short* __restrict__ nh_t)
{
    const int gtid = blockIdx.x * 256 + threadIdx.x;
    const int wv   = gtid >> 6;
    const int lane = threadIdx.x & 63;
    const int b = wv >> 6;
    const int f = wv & 63;

    const unsigned short* vt = lvt + ((size_t)(b*F_ + f))*L_ + lane*64;
    const float rootf = root[b*F_ + f];
    short8 xv[8]; float nv[8]; float gv[8];
    #pragma unroll
    for (int g = 0; g < 8; ++g) {
        xv[g] = *(const short8*)(vt + g*8);
        nv[g] = node_v[((size_t)(b*N_ + lane*8 + g))*F_ + f];
        float s8 = 0.f;
        #pragma unroll
        for (int j = 0; j < 8; ++j) s8 += bf2f((unsigned short)xv[g][j]);
        gv[g] = (s8 + 8.f*(rootf + nv[g])) * (1.f/3.f);
    }

    float s[9];
    s[8] = 0.f;
    #pragma unroll
    for (int j = 7; j >= 0; --j) s[j] = s[j+1] + gv[j];

    float x = s[0];
    const float lsum = x;
    #pragma unroll
    for (int off = 1; off < 64; off <<= 1) {
        float t = __shfl_down(x, off);
        if (lane + off < 64) x += t;
    }
    const float excl = x - lsum;   // suffix sum over lanes > lane

    const float* aggb = agg + (size_t)b*L_ + lane*64;
    unsigned short out8[8];
    #pragma unroll
    for (int g = 0; g < 8; ++g) {
        const float4 a0 = *(const float4*)(aggb + g*8);
        const float4 a1 = *(const float4*)(aggb + g*8 + 4);
        const float av[8] = {a0.x,a0.y,a0.z,a0.w, a1.x,a1.y,a1.z,a1.w};
        float mx = av[0];
        #pragma unroll
        for (int cc = 1; cc < 8; ++cc) mx = fmaxf(mx, av[cc]);
        float wgt[8]; float wsum = 0.f;
        #pragma unroll
        for (int cc = 0; cc < 8; ++cc) { wgt[cc] = __expf(av[cc] - mx); wsum += wgt[cc]; }

        const float tn = excl + s[g+1];
        float run = 0.f, acc = 0.f;
        #pragma unroll
        for (int cc = 7; cc >= 0; --cc) {
            const int ll = lane*64 + g*8 + cc;
            const float interp = (rootf + nv[g] + bf2f((unsigned short)xv[g][cc])) * (1.f/3.f);
            run += interp;
            const float up = (tn + run) / (float)(L_ - ll);
            acc = fmaf(wgt[cc], up, acc);
        }
        out8[g] = f2bf(acc / wsum);
    }
    *(uint4*)&nh_t[((size_t)(b*F_ + f))*N_ + lane*8] = *(const uint4*)out8;
}

// ---------------------------------------------------------------------------
// MFMA dual-softmax attention (round-9 verified: SLICES=8, 512 x 8-wave
// blocks = 16 waves/CU; bf16 pacc). Unchanged.
// ---------------------------------------------------------------------------
__global__ __launch_bounds__(512, 4)
void attn_kernel(const unsigned short* __restrict__ qb,
                 const unsigned short* __restrict__ nk,
                 const unsigned short* __restrict__ nht,
                 const unsigned short* __restrict__ lk,
                 const unsigned short* __restrict__ lvt,
                 unsigned short* __restrict__ pacc, float* __restrict__ pd)
{
    __shared__ unsigned short Ks[2][64*KSTR];   // 18 KB
    __shared__ unsigned short Vt[2][64*KSTR];   // 18 KB

    const int wg  = (blockIdx.x & 7) * 64 + (blockIdx.x >> 3);
    const int b   = wg >> 6;
    const int sl  = (wg >> 3) & 7;
    const int t0  = (wg & 7) * 128;

    const int tid = threadIdx.x;
    const int w   = tid >> 6;
    const int l   = tid & 63;
    const int c   = l & 15;
    const int h   = l >> 4;
    const int sm  = tid >> 3;
    const int sc  = tid & 7;

    const unsigned short* qrow = qb + ((size_t)(b*T_ + t0 + w*16 + c))*F_ + 8*h;
    const short8 qf0 = *(const short8*)qrow;
    const short8 qf1 = *(const short8*)(qrow + 32);

    f32x4 accN[4] = {{0,0,0,0},{0,0,0,0},{0,0,0,0},{0,0,0,0}};
    f32x4 accL[4] = {{0,0,0,0},{0,0,0,0},{0,0,0,0},{0,0,0,0}};
    float dsN = 0.f, dsL = 0.f;

    const unsigned short* Knb = nk  + (size_t)b*N_*F_;
    const unsigned short* Klb = lk  + (size_t)b*L_*F_;
    const unsigned short* Vnb = nht + (size_t)b*F_*N_;   // [F][N]
    const unsigned short* Vlb = lvt + (size_t)b*F_*L_;   // [F][L]

    const int ti0 = sl * TPS;

    uint4 sk0, sv0;
    auto load_tile = [&](int ti) {
        if (ti < 8) {
            sk0 = *(const uint4*)(Knb + (size_t)ti*64*F_ + sm*64 + sc*8);
            sv0 = *(const uint4*)(Vnb + (size_t)sm*N_ + ti*64 + sc*8);
        } else {
            sk0 = *(const uint4*)(Klb + (size_t)(ti-8)*64*F_ + sm*64 + sc*8);
            sv0 = *(const uint4*)(Vlb + (size_t)sm*L_ + (ti-8)*64 + sc*8);
        }
    };
    auto write_tile = [&](int pb) {
        *(uint4*)&Ks[pb][sm*KSTR + sc*8] = sk0;
        *(uint4*)&Vt[pb][sm*KSTR + sc*8] = sv0;
    };

    load_tile(ti0);
    write_tile(0);
    __syncthreads();

    const int srcA = c + 16*((2*h) & 3);
    const int srcB = c + 16*((2*h + 1) & 3);
    const int hs   = h >> 1;

    for (int i = 0; i < TPS; ++i) {
        const int  ti  = ti0 + i;
        const bool isN = ti < 8;
        const int  pb  = i & 1;
        const bool nxt = (i + 1 < TPS);
        if (nxt) load_tile(ti + 1);

        f32x4 st[4] = {{0,0,0,0},{0,0,0,0},{0,0,0,0},{0,0,0,0}};
        #pragma unroll
        for (int ss = 0; ss < 4; ++ss) {
            const short8 kf0 = *(const short8*)&Ks[pb][(16*ss + c)*KSTR + 8*h];
            st[ss] = __builtin_amdgcn_mfma_f32_16x16x32_bf16(kf0, qf0, st[ss], 0,0,0);
            const short8 kf1 = *(const short8*)&Ks[pb][(16*ss + c)*KSTR + 32 + 8*h];
            st[ss] = __builtin_amdgcn_mfma_f32_16x16x32_bf16(kf1, qf1, st[ss], 0,0,0);
        }

        unsigned pk0[4], pk1[4];
        float psum = 0.f;
        #pragma unroll
        for (int ss = 0; ss < 4; ++ss) {
            #pragma unroll
            for (int r = 0; r < 4; ++r) { st[ss][r] = __expf(st[ss][r]); psum += st[ss][r]; }
            pk0[ss] = pack_bf(st[ss][0], st[ss][1]);
            pk1[ss] = pack_bf(st[ss][2], st[ss][3]);
        }
        if (isN) dsN += psum; else dsL += psum;

        #pragma unroll
        for (int k00 = 0; k00 < 2; ++k00) {
            const unsigned d0a = __shfl(pk0[2*k00+0], srcA);
            const unsigned d0b = __shfl(pk0[2*k00+1], srcA);
            const unsigned d1a = __shfl(pk1[2*k00+0], srcA);
            const unsigned d1b = __shfl(pk1[2*k00+1], srcA);
            const unsigned d2a = __shfl(pk0[2*k00+0], srcB);
            const unsigned d2b = __shfl(pk0[2*k00+1], srcB);
            const unsigned d3a = __shfl(pk1[2*k00+0], srcB);
            const unsigned d3b = __shfl(pk1[2*k00+1], srcB);
            const short8 bp = frag_from4(hs ? d0b : d0a, hs ? d1b : d1a,
                                         hs ? d2b : d2a, hs ? d3b : d3a);
            if (isN) {
                #pragma unroll
                for (int s2 = 0; s2 < 4; ++s2) {
                    const short8 af = *(const short8*)&Vt[pb][(16*s2 + c)*KSTR + 32*k00 + 8*h];
                    accN[s2] = __builtin_amdgcn_mfma_f32_16x16x32_bf16(af, bp, accN[s2], 0,0,0);
                }
            } else {
                #pragma unroll
                for (int s2 = 0; s2 < 4; ++s2) {
                    const short8 af = *(const short8*)&Vt[pb][(16*s2 + c)*KSTR + 32*k00 + 8*h];
                    accL[s2] = __builtin_amdgcn_mfma_f32_16x16x32_bf16(af, bp, accL[s2], 0,0,0);
                }
            }
        }

        if (nxt) {
            write_tile(pb ^ 1);
            __syncthreads();
        }
    }

    dsN += __shfl_xor(dsN, 16);  dsN += __shfl_xor(dsN, 32);
    dsL += __shfl_xor(dsL, 16);  dsL += __shfl_xor(dsL, 32);

    const int gt = b*T_ + t0 + w*16 + c;
    unsigned short* baseN = pacc + (((size_t)sl*(B_*T_) + gt)*2 + 0)*F_;
    unsigned short* baseL = baseN + F_;
    #pragma unroll
    for (int s2 = 0; s2 < 4; ++s2) {
        *(unsigned*)&baseN[s2*16 + 4*h]     = pack_bf(accN[s2][0], accN[s2][1]);
        *(unsigned*)&baseN[s2*16 + 4*h + 2] = pack_bf(accN[s2][2], accN[s2][3]);
        *(unsigned*)&baseL[s2*16 + 4*h]     = pack_bf(accL[s2][0], accL[s2][1]);
        *(unsigned*)&baseL[s2*16 + 4*h + 2] = pack_bf(accL[s2][2], accL[s2][3]);
    }
    if (h == 0) {
        pd[((size_t)sl*(B_*T_) + gt)*2 + 0] = dsN;
        pd[((size_t)sl*(B_*T_) + gt)*2 + 1] = dsL;
    }
}

// ---------------------------------------------------------------------------
// Combine slices + final feature softmax. One wave per target, lane = f.
// ---------------------------------------------------------------------------
__global__ __launch_bounds__(256)
void combine_kernel(const unsigned short* __restrict__ pacc,
                    const float* __restrict__ pd,
                    float* __restrict__ out)
{
    const int gt = (blockIdx.x * 256 + threadIdx.x) >> 6;
    const int f  = threadIdx.x & 63;

    float aN = 0.f, aL = 0.f, dN = 0.f, dL = 0.f;
    #pragma unroll
    for (int s = 0; s < SLICES; ++s) {
        const size_t base = ((size_t)s*(B_*T_) + gt)*2;
        aN += bf2f(pacc[(base + 0)*F_ + f]);
        aL += bf2f(pacc[(base + 1)*F_ + f]);
        dN += pd[base + 0];
        dL += pd[base + 1];
    }
    float lg = aN / dN + aL / dL;
    float mx = lg;
    #pragma unroll
    for (int off = 1; off < 64; off <<= 1) mx = fmaxf(mx, __shfl_xor(mx, off));
    const float e = __expf(lg - mx);
    float ssum = e;
    #pragma unroll
    for (int off = 1; off < 64; off <<= 1) ssum += __shfl_xor(ssum, off);
    out[(size_t)gt*F_ + f] = e / ssum;
}

// ---------------------------------------------------------------------------
extern "C" void kernel_launch(void* const* d_in, const int* in_sizes, int n_in,
                              void* d_out, int out_size, void* d_ws, size_t ws_size,
                              hipStream_t stream)
{
    const float* root   = (const float*)d_in[0];
    const float* node   = (const float*)d_in[1];
    const float* leaf   = (const float*)d_in[2];
    const float* target = (const float*)d_in[3];
    const float* Wq   = (const float*)d_in[4];
    const float* bq   = (const float*)d_in[5];
    const float* Wk   = (const float*)d_in[6];
    const float* bk   = (const float*)d_in[7];
    const float* Wv   = (const float*)d_in[8];
    const float* bv   = (const float*)d_in[9];
    const float* Wagg = (const float*)d_in[10];
    const float* bagg = (const float*)d_in[11];
    float* out = (float*)d_out;

    // workspace layout (bytes), ~29 MB
    char* wp = (char*)d_ws;
    unsigned short* q_bf  = (unsigned short*)wp; wp += (size_t)B_*T_*F_*2;       // 1 MB
    unsigned short* nk_bf = (unsigned short*)wp; wp += (size_t)B_*N_*F_*2;       // 0.5 MB
    unsigned short* lk_bf = (unsigned short*)wp; wp += (size_t)B_*L_*F_*2;       // 4 MB
    unsigned short* lvt   = (unsigned short*)wp; wp += (size_t)B_*F_*L_*2;       // 4 MB
    unsigned short* nht   = (unsigned short*)wp; wp += (size_t)B_*F_*N_*2;       // 0.5 MB
    unsigned short* Wq_t  = (unsigned short*)wp; wp += (size_t)64*D_*2;          // 64 KB
    unsigned short* Wkv_t = (unsigned short*)wp; wp += (size_t)128*D_*2;         // 128 KB
    float* node_v = (float*)wp; wp += (size_t)B_*N_*F_*4;                        // 1 MB
    float* agg    = (float*)wp; wp += (size_t)B_*L_*4;                           // 128 KB
    float* bq_s   = (float*)wp; wp += 512;
    float* bkv    = (float*)wp; wp += 512;
    unsigned short* pacc = (unsigned short*)wp; wp += (size_t)SLICES*B_*T_*2*F_*2; // 16.8 MB
    float* pd     = (float*)wp;                                                  // 512 KB

    prep_kernel<<<193, 64, 0, stream>>>(Wq, bq, Wk, bk, Wv, bv, Wq_t, Wkv_t, bq_s, bkv);
    proj_all<<<704, 512, 0, stream>>>(target, node, leaf, Wq_t, Wkv_t, bq_s, bkv,
                                      Wagg, bagg, q_bf, nk_bf, node_v, lk_bf, lvt, agg);
    scan_nh_kernel<<<128, 256, 0, stream>>>(lvt, node_v, root, agg, nht);
    attn_kernel<<<B_*(T_/128)*SLICES, 512, 0, stream>>>(q_bf, nk_bf, nht, lk_bf, lvt, pacc, pd);
    combine_kernel<<<(B_*T_)/4, 256, 0, stream>>>(pacc, pd, out);
}

// Round 22
// 78.441 us; speedup vs baseline: 1.2617x; 1.2617x over previous
//
#include <hip/hip_runtime.h>

// DecoderAttention: B=8, T=1024, N=512, L=4096, D=512, F=64, BR=8
#define B_ 8
#define T_ 1024
#define N_ 512
#define L_ 4096
#define D_ 512
#define F_ 64
#define SLICES 8
#define TPS 9     // tiles per slice (72 total: 8 node + 64 leaf)
#define KSTR 72   // attn LDS row stride (bf16) for K / V^T tiles
#define XSTR 264  // proj LDS row stride (bf16) for 256-wide k-chunks

typedef __attribute__((ext_vector_type(8))) short short8;
typedef __attribute__((ext_vector_type(4))) float f32x4;

__device__ __forceinline__ unsigned short f2bf(float x){
    unsigned u = __builtin_bit_cast(unsigned, x);
    u += 0x7FFFu + ((u >> 16) & 1u);           // RNE
    return (unsigned short)(u >> 16);
}
__device__ __forceinline__ unsigned pack_bf(float lo, float hi){
    return (unsigned)f2bf(lo) | ((unsigned)f2bf(hi) << 16);
}
__device__ __forceinline__ float bf2f(unsigned short s){
    return __builtin_bit_cast(float, ((unsigned)s) << 16);
}
__device__ __forceinline__ short8 frag_from4(unsigned d0, unsigned d1, unsigned d2, unsigned d3){
    union { unsigned u[4]; short8 s; } t;
    t.u[0] = d0; t.u[1] = d1; t.u[2] = d2; t.u[3] = d3;
    return t.s;
}

// ---------------------------------------------------------------------------
// Weight prep: transposed bf16 weights + bias vectors.
// ---------------------------------------------------------------------------
__global__ __launch_bounds__(64)
void prep_kernel(const float* __restrict__ Wq, const float* __restrict__ bq,
                 const float* __restrict__ Wk, const float* __restrict__ bk,
                 const float* __restrict__ Wv, const float* __restrict__ bv,
                 unsigned short* __restrict__ Wq_t, unsigned short* __restrict__ Wkv_t,
                 float* __restrict__ bq_s, float* __restrict__ bkv)
{
    const int n = blockIdx.x;
    const int lane = threadIdx.x;
    if (n == 192) {
        bq_s[lane]   = bq[lane] * 0.125f;
        bkv[lane]    = bk[lane];
        bkv[64+lane] = bv[lane];
        return;
    }
    const int d0 = lane * 8;
    unsigned short t[8];
    if (n < 64) {
        #pragma unroll
        for (int j = 0; j < 8; ++j) t[j] = f2bf(Wq[(size_t)(d0+j)*F_ + n] * 0.125f);
        *(uint4*)&Wq_t[(size_t)n*D_ + d0] = make_uint4(
            (unsigned)t[0]|((unsigned)t[1]<<16), (unsigned)t[2]|((unsigned)t[3]<<16),
            (unsigned)t[4]|((unsigned)t[5]<<16), (unsigned)t[6]|((unsigned)t[7]<<16));
    } else {
        const int nn  = n - 64;
        const float* W = (nn < 64) ? Wk : Wv;
        const int col = nn & 63;
        #pragma unroll
        for (int j = 0; j < 8; ++j) t[j] = f2bf(W[(size_t)(d0+j)*F_ + col]);
        *(uint4*)&Wkv_t[(size_t)nn*D_ + d0] = make_uint4(
            (unsigned)t[0]|((unsigned)t[1]<<16), (unsigned)t[2]|((unsigned)t[3]<<16),
            (unsigned)t[4]|((unsigned)t[5]<<16), (unsigned)t[6]|((unsigned)t[7]<<16));
    }
}

// ---------------------------------------------------------------------------
// Fused MFMA projection (R16, best measured; reproduced 79.0/78.8 µs total).
// K split into 2 chunks of 256 so LDS = 76.8 KB -> TWO blocks/CU;
// stage/compute phases overlap across co-resident blocks. 1024 thr,
// 16 waves: wave w = (n-tile w&3, m w>>2). Phase(kc, p): stage {Xs(kc) if
// p==0} + Ws(kc,p); sync; 8 kk-steps of 2 ds_read_b128 + 1 MFMA; sync.
// agg partials computed inside p1 phases.
// NOTE (R13/R14/R17/R18/R19/R21 post-mortems): register-staged pipelines
// are sunk or spilled by the allocator in this structure regardless of
// launch bounds; narrower k-chunks inflate W re-reads. Do not reintroduce.
// ---------------------------------------------------------------------------
template<int MODE>
__device__ __forceinline__ void proj_body(
    int r0, unsigned short* Xs, unsigned short* Ws, unsigned short* Vt_lds,
    const float* __restrict__ X,
    const unsigned short* __restrict__ Wt,
    const float* __restrict__ bias,
    const float* __restrict__ Wagg, const float* __restrict__ bagg,
    unsigned short* __restrict__ outK, float* __restrict__ outVf,
    unsigned short* __restrict__ outVt, float* __restrict__ outAgg)
{
    constexpr int NPASS = (MODE == 0) ? 1 : 2;
    const int tid = threadIdx.x;              // 0..1023
    const int l = tid & 63, c = l & 15, h = l >> 4;
    const int w  = tid >> 6;                  // wave 0..15
    const int nt = w & 3;                     // n-tile within pass
    const int m  = w >> 2;                    // m-subtile

    f32x4 acc0 = {0,0,0,0};
    f32x4 acc1 = {0,0,0,0};
    float pa = 0.f;                           // agg partial (MODE 2)

    #pragma unroll
    for (int kc = 0; kc < 2; ++kc) {
        // ---- stage Xs(kc): 64 rows x 256 f32 -> bf16 (4 float4/thread) ----
        #pragma unroll
        for (int j = 0; j < 4; ++j) {
            const int s = tid + j * 1024;     // slot; 64 float4 per row
            const int row = s >> 6, col = s & 63;
            const float4 v = *(const float4*)(X + (size_t)(r0+row)*D_ + kc*256 + col*4);
            *(uint2*)&Xs[row*XSTR + col*4] =
                make_uint2(pack_bf(v.x, v.y), pack_bf(v.z, v.w));
        }
        // ---- stage Ws(kc, pass 0): 64 cols x 256 bf16 (2 uint4/thread) ----
        {
            const int r = tid >> 4, ch = tid & 15;
            #pragma unroll
            for (int j = 0; j < 2; ++j) {
                const int u = ch + j*16;
                *(uint4*)&Ws[r*XSTR + u*8] =
                    *(const uint4*)(Wt + (size_t)r*D_ + kc*256 + u*8);
            }
        }
        __syncthreads();

        // ---- pass 0 compute: 8 kk-steps ----
        #pragma unroll
        for (int kk = 0; kk < 8; ++kk) {
            const short8 bfr = *(const short8*)&Ws[(16*nt + c)*XSTR + kk*32 + 8*h];
            const short8 af  = *(const short8*)&Xs[(16*m  + c)*XSTR + kk*32 + 8*h];
            acc0 = __builtin_amdgcn_mfma_f32_16x16x32_bf16(af, bfr, acc0, 0,0,0);
        }
        __syncthreads();

        if constexpr (NPASS == 2) {
            // ---- stage Ws(kc, pass 1) ----
            {
                const int r = tid >> 4, ch = tid & 15;
                #pragma unroll
                for (int j = 0; j < 2; ++j) {
                    const int u = ch + j*16;
                    *(uint4*)&Ws[r*XSTR + u*8] =
                        *(const uint4*)(Wt + (size_t)(64 + r)*D_ + kc*256 + u*8);
                }
            }
            __syncthreads();
            // ---- pass 1 compute ----
            #pragma unroll
            for (int kk = 0; kk < 8; ++kk) {
                const short8 bfr = *(const short8*)&Ws[(16*nt + c)*XSTR + kk*32 + 8*h];
                const short8 af  = *(const short8*)&Xs[(16*m  + c)*XSTR + kk*32 + 8*h];
                acc1 = __builtin_amdgcn_mfma_f32_16x16x32_bf16(af, bfr, acc1, 0,0,0);
            }
            // ---- agg partial for this k-chunk (Xs still valid here) ----
            if constexpr (MODE == 2) {
                const int row = tid >> 4, qd = tid & 15;
                const unsigned short* xr = &Xs[row*XSTR + qd*16];
                const float* wr = Wagg + kc*256 + qd*16;
                #pragma unroll
                for (int j = 0; j < 2; ++j) {
                    const short8 xv = *(const short8*)(xr + j*8);
                    const float4 wa0 = *(const float4*)(wr + j*8);
                    const float4 wa1 = *(const float4*)(wr + j*8 + 4);
                    pa += bf2f((unsigned short)xv[0])*wa0.x + bf2f((unsigned short)xv[1])*wa0.y
                        + bf2f((unsigned short)xv[2])*wa0.z + bf2f((unsigned short)xv[3])*wa0.w
                        + bf2f((unsigned short)xv[4])*wa1.x + bf2f((unsigned short)xv[5])*wa1.y
                        + bf2f((unsigned short)xv[6])*wa1.z + bf2f((unsigned short)xv[7])*wa1.w;
                }
            }
            __syncthreads();
        }
    }

    // ---- epilogue (R12/R15-verified mapping): row=r0+16m+4h+r, col=16nt+c
    {
        const float bc0 = bias[16*nt + c];
        #pragma unroll
        for (int r = 0; r < 4; ++r) {
            const int row = r0 + 16*m + 4*h + r;
            outK[(size_t)row*F_ + 16*nt + c] = f2bf(acc0[r] + bc0);
        }
    }
    if constexpr (NPASS == 2) {
        const float bc1 = bias[64 + 16*nt + c];
        #pragma unroll
        for (int r = 0; r < 4; ++r) {
            const int row = r0 + 16*m + 4*h + r;
            const float v = acc1[r] + bc1;
            if constexpr (MODE == 1) {
                outVf[(size_t)row*F_ + 16*nt + c] = v;
            } else {
                Vt_lds[(16*nt + c)*72 + 16*m + 4*h + r] = f2bf(v);
            }
        }
    }

    if constexpr (MODE == 2) {
        // agg: reduce over the 16 qd lanes, write one logit per leaf row
        {
            const int row = tid >> 4, qd = tid & 15;
            pa += __shfl_xor(pa, 1);
            pa += __shfl_xor(pa, 2);
            pa += __shfl_xor(pa, 4);
            pa += __shfl_xor(pa, 8);
            if (qd == 0) outAgg[r0 + row] = pa + bagg[0];
        }
        __syncthreads();              // Vt_lds complete
        // coalesced V^T writeout: f = tid>>4, 4-leaf segment
        {
            const int f = tid >> 4, seg = tid & 15;
            const int b = r0 >> 12, l0 = r0 & (L_ - 1);
            const uint2 a0 = *(const uint2*)&Vt_lds[f*72 + seg*4];
            *(uint2*)(outVt + ((size_t)(b*F_ + f))*L_ + l0 + seg*4) = a0;
        }
    }
}

// Fused projections: blocks 0..511 leaf, 512..639 target(q), 640..703 node.
__global__ __launch_bounds__(1024, 8)
void proj_all(const float* __restrict__ target, const float* __restrict__ node,
              const float* __restrict__ leaf,
              const unsigned short* __restrict__ Wq_t,
              const unsigned short* __restrict__ Wkv_t,
              const float* __restrict__ bq_s, const float* __restrict__ bkv,
              const float* __restrict__ Wagg, const float* __restrict__ bagg,
              unsigned short* __restrict__ q_bf, unsigned short* __restrict__ nk_bf,
              float* __restrict__ node_v, unsigned short* __restrict__ lk_bf,
              unsigned short* __restrict__ lvt, float* __restrict__ agg)
{
    __shared__ unsigned short Xs[64 * XSTR];      // 33.8 KB
    __shared__ unsigned short Ws[64 * XSTR];      // 33.8 KB
    __shared__ unsigned short Vt_lds[64 * 72];    // 9.2 KB -> 76.8 KB total
    const int blk = blockIdx.x;
    if (blk < 512) {
        proj_body<2>(blk*64, Xs, Ws, Vt_lds, leaf, Wkv_t, bkv, Wagg, bagg,
                     lk_bf, nullptr, lvt, agg);
    } else if (blk < 640) {
        proj_body<0>((blk-512)*64, Xs, Ws, Vt_lds, target, Wq_t, bq_s, nullptr, nullptr,
                     q_bf, nullptr, nullptr, nullptr);
    } else {
        proj_body<1>((blk-640)*64, Xs, Ws, Vt_lds, node, Wkv_t, bkv, nullptr, nullptr,
                     nk_bf, node_v, nullptr, nullptr);
    }
}

// ---------------------------------------------------------------------------
// Fused suffix-scan + node_hat (verified round 9). One wave per (b,f).
// ---------------------------------------------------------------------------
__global__ __launch_bounds__(256)
void scan_nh_kernel(const unsigned short* __restrict__ lvt,
                    const float* __restrict__ node_v,
                    const float* __restrict__ root,
                    const float* __restrict__ agg,
                    unsigned short* __restrict__ nh_t)
{
    const int gtid = blockIdx.x * 256 + threadIdx.x;
    const int wv   = gtid >> 6;
    const int lane = threadIdx.x & 63;
    const int b = wv >> 6;
    const int f = wv & 63;

    const unsigned short* vt = lvt + ((size_t)(b*F_ + f))*L_ + lane*64;
    const float rootf = root[b*F_ + f];
    short8 xv[8]; float nv[8]; float gv[8];
    #pragma unroll
    for (int g = 0; g < 8; ++g) {
        xv[g] = *(const short8*)(vt + g*8);
        nv[g] = node_v[((size_t)(b*N_ + lane*8 + g))*F_ + f];
        float s8 = 0.f;
        #pragma unroll
        for (int j = 0; j < 8; ++j) s8 += bf2f((unsigned short)xv[g][j]);
        gv[g] = (s8 + 8.f*(rootf + nv[g])) * (1.f/3.f);
    }

    float s[9];
    s[8] = 0.f;
    #pragma unroll
    for (int j = 7; j >= 0; --j) s[j] = s[j+1] + gv[j];

    float x = s[0];
    const float lsum = x;
    #pragma unroll
    for (int off = 1; off < 64; off <<= 1) {
        float t = __shfl_down(x, off);
        if (lane + off < 64) x += t;
    }
    const float excl = x - lsum;   // suffix sum over lanes > lane

    const float* aggb = agg + (size_t)b*L_ + lane*64;
    unsigned short out8[8];
    #pragma unroll
    for (int g = 0; g < 8; ++g) {
        const float4 a0 = *(const float4*)(aggb + g*8);
        const float4 a1 = *(const float4*)(aggb + g*8 + 4);
        const float av[8] = {a0.x,a0.y,a0.z,a0.w, a1.x,a1.y,a1.z,a1.w};
        float mx = av[0];
        #pragma unroll
        for (int cc = 1; cc < 8; ++cc) mx = fmaxf(mx, av[cc]);
        float wgt[8]; float wsum = 0.f;
        #pragma unroll
        for (int cc = 0; cc < 8; ++cc) { wgt[cc] = __expf(av[cc] - mx); wsum += wgt[cc]; }

        const float tn = excl + s[g+1];
        float run = 0.f, acc = 0.f;
        #pragma unroll
        for (int cc = 7; cc >= 0; --cc) {
            const int ll = lane*64 + g*8 + cc;
            const float interp = (rootf + nv[g] + bf2f((unsigned short)xv[g][cc])) * (1.f/3.f);
            run += interp;
            const float up = (tn + run) / (float)(L_ - ll);
            acc = fmaf(wgt[cc], up, acc);
        }
        out8[g] = f2bf(acc / wsum);
    }
    *(uint4*)&nh_t[((size_t)(b*F_ + f))*N_ + lane*8] = *(const uint4*)out8;
}

// ---------------------------------------------------------------------------
// MFMA dual-softmax attention (round-9 verified: SLICES=8, 512 x 8-wave
// blocks = 16 waves/CU; bf16 pacc). Unchanged.
// ---------------------------------------------------------------------------
__global__ __launch_bounds__(512, 4)
void attn_kernel(const unsigned short* __restrict__ qb,
                 const unsigned short* __restrict__ nk,
                 const unsigned short* __restrict__ nht,
                 const unsigned short* __restrict__ lk,
                 const unsigned short* __restrict__ lvt,
                 unsigned short* __restrict__ pacc, float* __restrict__ pd)
{
    __shared__ unsigned short Ks[2][64*KSTR];   // 18 KB
    __shared__ unsigned short Vt[2][64*KSTR];   // 18 KB

    const int wg  = (blockIdx.x & 7) * 64 + (blockIdx.x >> 3);
    const int b   = wg >> 6;
    const int sl  = (wg >> 3) & 7;
    const int t0  = (wg & 7) * 128;

    const int tid = threadIdx.x;
    const int w   = tid >> 6;
    const int l   = tid & 63;
    const int c   = l & 15;
    const int h   = l >> 4;
    const int sm  = tid >> 3;
    const int sc  = tid & 7;

    const unsigned short* qrow = qb + ((size_t)(b*T_ + t0 + w*16 + c))*F_ + 8*h;
    const short8 qf0 = *(const short8*)qrow;
    const short8 qf1 = *(const short8*)(qrow + 32);

    f32x4 accN[4] = {{0,0,0,0},{0,0,0,0},{0,0,0,0},{0,0,0,0}};
    f32x4 accL[4] = {{0,0,0,0},{0,0,0,0},{0,0,0,0},{0,0,0,0}};
    float dsN = 0.f, dsL = 0.f;

    const unsigned short* Knb = nk  + (size_t)b*N_*F_;
    const unsigned short* Klb = lk  + (size_t)b*L_*F_;
    const unsigned short* Vnb = nht + (size_t)b*F_*N_;   // [F][N]
    const unsigned short* Vlb = lvt + (size_t)b*F_*L_;   // [F][L]

    const int ti0 = sl * TPS;

    uint4 sk0, sv0;
    auto load_tile = [&](int ti) {
        if (ti < 8) {
            sk0 = *(const uint4*)(Knb + (size_t)ti*64*F_ + sm*64 + sc*8);
            sv0 = *(const uint4*)(Vnb + (size_t)sm*N_ + ti*64 + sc*8);
        } else {
            sk0 = *(const uint4*)(Klb + (size_t)(ti-8)*64*F_ + sm*64 + sc*8);
            sv0 = *(const uint4*)(Vlb + (size_t)sm*L_ + (ti-8)*64 + sc*8);
        }
    };
    auto write_tile = [&](int pb) {
        *(uint4*)&Ks[pb][sm*KSTR + sc*8] = sk0;
        *(uint4*)&Vt[pb][sm*KSTR + sc*8] = sv0;
    };

    load_tile(ti0);
    write_tile(0);
    __syncthreads();

    const int srcA = c + 16*((2*h) & 3);
    const int srcB = c + 16*((2*h + 1) & 3);
    const int hs   = h >> 1;

    for (int i = 0; i < TPS; ++i) {
        const int  ti  = ti0 + i;
        const bool isN = ti < 8;
        const int  pb  = i & 1;
        const bool nxt = (i + 1 < TPS);
        if (nxt) load_tile(ti + 1);

        f32x4 st[4] = {{0,0,0,0},{0,0,0,0},{0,0,0,0},{0,0,0,0}};
        #pragma unroll
        for (int ss = 0; ss < 4; ++ss) {
            const short8 kf0 = *(const short8*)&Ks[pb][(16*ss + c)*KSTR + 8*h];
            st[ss] = __builtin_amdgcn_mfma_f32_16x16x32_bf16(kf0, qf0, st[ss], 0,0,0);
            const short8 kf1 = *(const short8*)&Ks[pb][(16*ss + c)*KSTR + 32 + 8*h];
            st[ss] = __builtin_amdgcn_mfma_f32_16x16x32_bf16(kf1, qf1, st[ss], 0,0,0);
        }

        unsigned pk0[4], pk1[4];
        float psum = 0.f;
        #pragma unroll
        for (int ss = 0; ss < 4; ++ss) {
            #pragma unroll
            for (int r = 0; r < 4; ++r) { st[ss][r] = __expf(st[ss][r]); psum += st[ss][r]; }
            pk0[ss] = pack_bf(st[ss][0], st[ss][1]);
            pk1[ss] = pack_bf(st[ss][2], st[ss][3]);
        }
        if (isN) dsN += psum; else dsL += psum;

        #pragma unroll
        for (int k00 = 0; k00 < 2; ++k00) {
            const unsigned d0a = __shfl(pk0[2*k00+0], srcA);
            const unsigned d0b = __shfl(pk0[2*k00+1], srcA);
            const unsigned d1a = __shfl(pk1[2*k00+0], srcA);
            const unsigned d1b = __shfl(pk1[2*k00+1], srcA);
            const unsigned d2a = __shfl(pk0[2*k00+0], srcB);
            const unsigned d2b = __shfl(pk0[2*k00+1], srcB);
            const unsigned d3a = __shfl(pk1[2*k00+0], srcB);
            const unsigned d3b = __shfl(pk1[2*k00+1], srcB);
            const short8 bp = frag_from4(hs ? d0b : d0a, hs ? d1b : d1a,
                                         hs ? d2b : d2a, hs ? d3b : d3a);
            if (isN) {
                #pragma unroll
                for (int s2 = 0; s2 < 4; ++s2) {
                    const short8 af = *(const short8*)&Vt[pb][(16*s2 + c)*KSTR + 32*k00 + 8*h];
                    accN[s2] = __builtin_amdgcn_mfma_f32_16x16x32_bf16(af, bp, accN[s2], 0,0,0);
                }
            } else {
                #pragma unroll
                for (int s2 = 0; s2 < 4; ++s2) {
                    const short8 af = *(const short8*)&Vt[pb][(16*s2 + c)*KSTR + 32*k00 + 8*h];
                    accL[s2] = __builtin_amdgcn_mfma_f32_16x16x32_bf16(af, bp, accL[s2], 0,0,0);
                }
            }
        }

        if (nxt) {
            write_tile(pb ^ 1);
            __syncthreads();
        }
    }

    dsN += __shfl_xor(dsN, 16);  dsN += __shfl_xor(dsN, 32);
    dsL += __shfl_xor(dsL, 16);  dsL += __shfl_xor(dsL, 32);

    const int gt = b*T_ + t0 + w*16 + c;
    unsigned short* baseN = pacc + (((size_t)sl*(B_*T_) + gt)*2 + 0)*F_;
    unsigned short* baseL = baseN + F_;
    #pragma unroll
    for (int s2 = 0; s2 < 4; ++s2) {
        *(unsigned*)&baseN[s2*16 + 4*h]     = pack_bf(accN[s2][0], accN[s2][1]);
        *(unsigned*)&baseN[s2*16 + 4*h + 2] = pack_bf(accN[s2][2], accN[s2][3]);
        *(unsigned*)&baseL[s2*16 + 4*h]     = pack_bf(accL[s2][0], accL[s2][1]);
        *(unsigned*)&baseL[s2*16 + 4*h + 2] = pack_bf(accL[s2][2], accL[s2][3]);
    }
    if (h == 0) {
        pd[((size_t)sl*(B_*T_) + gt)*2 + 0] = dsN;
        pd[((size_t)sl*(B_*T_) + gt)*2 + 1] = dsL;
    }
}

// ---------------------------------------------------------------------------
// Combine slices + final feature softmax. One wave per target, lane = f.
// ---------------------------------------------------------------------------
__global__ __launch_bounds__(256)
void combine_kernel(const unsigned short* __restrict__ pacc,
                    const float* __restrict__ pd,
                    float* __restrict__ out)
{
    const int gt = (blockIdx.x * 256 + threadIdx.x) >> 6;
    const int f  = threadIdx.x & 63;

    float aN = 0.f, aL = 0.f, dN = 0.f, dL = 0.f;
    #pragma unroll
    for (int s = 0; s < SLICES; ++s) {
        const size_t base = ((size_t)s*(B_*T_) + gt)*2;
        aN += bf2f(pacc[(base + 0)*F_ + f]);
        aL += bf2f(pacc[(base + 1)*F_ + f]);
        dN += pd[base + 0];
        dL += pd[base + 1];
    }
    float lg = aN / dN + aL / dL;
    float mx = lg;
    #pragma unroll
    for (int off = 1; off < 64; off <<= 1) mx = fmaxf(mx, __shfl_xor(mx, off));
    const float e = __expf(lg - mx);
    float ssum = e;
    #pragma unroll
    for (int off = 1; off < 64; off <<= 1) ssum += __shfl_xor(ssum, off);
    out[(size_t)gt*F_ + f] = e / ssum;
}

// ---------------------------------------------------------------------------
extern "C" void kernel_launch(void* const* d_in, const int* in_sizes, int n_in,
                              void* d_out, int out_size, void* d_ws, size_t ws_size,
                              hipStream_t stream)
{
    const float* root   = (const float*)d_in[0];
    const float* node   = (const float*)d_in[1];
    const float* leaf   = (const float*)d_in[2];
    const float* target = (const float*)d_in[3];
    const float* Wq   = (const float*)d_in[4];
    const float* bq   = (const float*)d_in[5];
    const float* Wk   = (const float*)d_in[6];
    const float* bk   = (const float*)d_in[7];
    const float* Wv   = (const float*)d_in[8];
    const float* bv   = (const float*)d_in[9];
    const float* Wagg = (const float*)d_in[10];
    const float* bagg = (const float*)d_in[11];
    float* out = (float*)d_out;

    // workspace layout (bytes), ~29 MB
    char* wp = (char*)d_ws;
    unsigned short* q_bf  = (unsigned short*)wp; wp += (size_t)B_*T_*F_*2;       // 1 MB
    unsigned short* nk_bf = (unsigned short*)wp; wp += (size_t)B_*N_*F_*2;       // 0.5 MB
    unsigned short* lk_bf = (unsigned short*)wp; wp += (size_t)B_*L_*F_*2;       // 4 MB
    unsigned short* lvt   = (unsigned short*)wp; wp += (size_t)B_*F_*L_*2;       // 4 MB
    unsigned short* nht   = (unsigned short*)wp; wp += (size_t)B_*F_*N_*2;       // 0.5 MB
    unsigned short* Wq_t  = (unsigned short*)wp; wp += (size_t)64*D_*2;          // 64 KB
    unsigned short* Wkv_t = (unsigned short*)wp; wp += (size_t)128*D_*2;         // 128 KB
    float* node_v = (float*)wp; wp += (size_t)B_*N_*F_*4;                        // 1 MB
    float* agg    = (float*)wp; wp += (size_t)B_*L_*4;                           // 128 KB
    float* bq_s   = (float*)wp; wp += 512;
    float* bkv    = (float*)wp; wp += 512;
    unsigned short* pacc = (unsigned short*)wp; wp += (size_t)SLICES*B_*T_*2*F_*2; // 16.8 MB
    float* pd     = (float*)wp;                                                  // 512 KB

    prep_kernel<<<193, 64, 0, stream>>>(Wq, bq, Wk, bk, Wv, bv, Wq_t, Wkv_t, bq_s, bkv);
    proj_all<<<704, 1024, 0, stream>>>(target, node, leaf, Wq_t, Wkv_t, bq_s, bkv,
                                       Wagg, bagg, q_bf, nk_bf, node_v, lk_bf, lvt, agg);
    scan_nh_kernel<<<128, 256, 0, stream>>>(lvt, node_v, root, agg, nht);
    attn_kernel<<<B_*(T_/128)*SLICES, 512, 0, stream>>>(q_bf, nk_bf, nht, lk_bf, lvt, pacc, pd);
    combine_kernel<<<(B_*T_)/4, 256, 0, stream>>>(pacc, pd, out);
}